// Round 17
// baseline (51.273 us; speedup 1.0000x reference)
//
#include <hip/hip_runtime.h>
#include <cmath>

// Fixed problem shape (reference setup_inputs): bs=16, nq=900, nc=80, nt=3200
#define NCC   80                 // classes
#define QT    8                  // queries per row-group
#define BLK   256                // threads per block
#define VT    4                  // targets per thread-tile (float4 store)
#define NT_C  3200               // targets
#define NQB_C 14400              // bs*nq rows
#define CPR   (NT_C / VT)        // 800 float4-columns per row-group
#define NRG   (NQB_C / QT)       // 1800 row-groups
#define TOTAL (NRG * CPR)        // 1,440,000 work items
#define NTILE 3                  // tiles per thread
#define WPB   (NTILE * BLK)      // 768 work items per block; 768<=800 => <=2 row-groups
#define CSTR  20                 // class-table row stride in floats (16B-aligned)

typedef float f32x4 __attribute__((ext_vector_type(4)));

__device__ __forceinline__ float cls_cost(float x) {
    // 2*(pos-neg) + 2  : COST_CLASS folded + giou-rewrite constant
    const float p   = 1.0f / (1.0f + __expf(-x));
    const float om  = 1.0f - p;
    const float pos = 0.25f * om * om * (-__logf(p  + 1e-8f));
    const float neg = 0.75f * p  * p  * (-__logf(om + 1e-8f));
    return 2.0f * (pos - neg) + 2.0f;
}

struct TileIn {
    int   labk[VT];
    float4 tb[VT];
    float  ta[VT];
    int    g8;
    unsigned obase;
};

__device__ __forceinline__ TileIn tile_load(
    int w, int rg0,
    const int* __restrict__ labels, const float* __restrict__ tboxes)
{
    TileIn t;
    const int rg = w / CPR;
    const int c  = w - rg * CPR;
    const int j  = c * VT;
    t.g8    = (rg - rg0) * QT;
    t.obase = (unsigned)(rg * QT) * NT_C + (unsigned)j;
    const int4 l4 = ((const int4*)labels)[c];
    t.labk[0] = l4.x; t.labk[1] = l4.y; t.labk[2] = l4.z; t.labk[3] = l4.w;
#pragma unroll
    for (int k = 0; k < VT; ++k) {
        t.tb[k] = ((const float4*)tboxes)[j + k];
        t.ta[k] = t.tb[k].z * t.tb[k].w;
    }
    return t;
}

// Compute + store one tile's 8 queries x 4 targets (R14 math, NT stores).
__device__ __forceinline__ void tile_compute(
    const TileIn& t,
    const float* __restrict__ s_cls, const float4* __restrict__ s_qb,
    float* __restrict__ out)
{
#pragma unroll
    for (int h = 0; h < 2; ++h) {
        const int qbase = t.g8 + h * 4;
        float4 c2v[VT];
#pragma unroll
        for (int k = 0; k < VT; ++k)
            c2v[k] = *(const float4*)&s_cls[t.labk[k] * CSTR + qbase];

        const unsigned offh = t.obase + (unsigned)h * 4u * NT_C;
#pragma unroll
        for (int q4 = 0; q4 < 4; ++q4) {
            const float4 qb = s_qb[qbase + q4];
            const float  qa = qb.z * qb.w;
            float res[VT];
#pragma unroll
            for (int k = 0; k < VT; ++k) {
                const float c2 = c2v[k][q4];
                const float d1 = qb.x - t.tb[k].x;
                const float d2 = qb.y - t.tb[k].y;
                const float d3 = qb.z - t.tb[k].z;
                const float d4 = qb.w - t.tb[k].w;
                const float sx = qb.z + t.tb[k].z;
                const float sy = qb.w + t.tb[k].w;
                const float dxr = fmaf(0.5f, sx, -fabsf(d1));
                const float dyr = fmaf(0.5f, sy, -fabsf(d2));
                const float dx  = fminf(fminf(dxr, qb.z), t.tb[k].z);   // v_min3
                const float dy  = fminf(fminf(dyr, qb.w), t.tb[k].w);
                const float iw  = fmaxf(dx, 0.0f);
                const float ih  = fmaxf(dy, 0.0f);
                const float inter = iw * ih;
                const float uni   = (qa + t.ta[k]) - inter;
                const float ew = sx - dx;
                const float eh = sy - dy;
                const float encl = ew * eh;
                const float r1 = __builtin_amdgcn_rcpf(fmaxf(uni,  1e-6f));
                const float r2 = __builtin_amdgcn_rcpf(fmaxf(encl, 1e-6f));
                const float l1 = (fabsf(d1) + fabsf(d2)) + (fabsf(d3) + fabsf(d4));
                float cc = fmaf(5.0f, l1, c2);
                cc = fmaf(-2.0f * inter, r1, cc);
                cc = fmaf(-2.0f * uni,  r2, cc);
                res[k] = cc;
            }
            f32x4 v = { res[0], res[1], res[2], res[3] };
            __builtin_nontemporal_store(
                v, (f32x4*)(out + offh + (unsigned)q4 * NT_C));
        }
    }
}

// ---------------- fast kernel ----------------------------------------------
// THREE software-pipelined tiles per thread (768 work items/block, 1875 blocks,
// exact): tile i+1's global loads are issued before tile i's compute, so each
// tile's NT-store drain hides under the next tile's compute. Staging redundancy
// and final-exit drain amortized over 96 outputs/thread.
__global__ __launch_bounds__(BLK) void cost_fast(
    const float* __restrict__ logits,   // [NQB_C, NCC]
    const float* __restrict__ pboxes,   // [NQB_C, 4] cxcywh
    const int*   __restrict__ labels,   // [NT_C]
    const float* __restrict__ tboxes,   // [NT_C, 4] cxcywh
    float*       __restrict__ out)      // [NQB_C, NT_C]
{
    __shared__ float4 s_clsv[NCC * (CSTR / 4)];     // [80][20] floats
    __shared__ float4 s_qb[2 * QT];                 // cxcywh
    float* s_cls = (float*)s_clsv;

    const int  w0   = blockIdx.x * WPB;
    const int  rg0  = w0 / CPR;
    const int  row0 = rg0 * QT;
    const bool two  = (((w0 + WPB - 1) / CPR) != rg0);  // spans 2 row-groups?

    // ---- tile 1 loads BEFORE the barrier (latency overlap with staging) ----
    TileIn t1 = tile_load(w0 + threadIdx.x, rg0, labels, tboxes);

    // ---- staging: LINEAR coalesced reads, LDS-scatter writes ----
    {
        const int nst = (two ? 2 * QT : QT) * NCC;   // 640 or 1280
        const float* src = logits + row0 * NCC;
        for (int t = threadIdx.x; t < nst; t += BLK) {
            const int ro  = t / NCC;                 // row offset 0..15
            const int lab = t - ro * NCC;
            s_cls[lab * CSTR + ro] = cls_cost(src[t]);
        }
    }
    const int ng = two ? 2 * QT : QT;
    if (threadIdx.x < ng) {
        s_qb[threadIdx.x] = ((const float4*)pboxes)[row0 + threadIdx.x];
    }
    __syncthreads();

    // ---- software pipeline: load t2 | compute t1 | load t3 | compute t2 | compute t3
    TileIn t2 = tile_load(w0 + BLK + threadIdx.x, rg0, labels, tboxes);
    tile_compute(t1, s_cls, s_qb, out);
    TileIn t3 = tile_load(w0 + 2 * BLK + threadIdx.x, rg0, labels, tboxes);
    tile_compute(t2, s_cls, s_qb, out);
    tile_compute(t3, s_cls, s_qb, out);
}

// ---------------- generic fallback ------------------------------------------
__global__ __launch_bounds__(BLK) void cost_generic(
    const float* __restrict__ logits, const float* __restrict__ pboxes,
    const int* __restrict__ labels, const float* __restrict__ tboxes,
    float* __restrict__ out, int NQB, int NT, int NC)
{
    extern __shared__ float smem[];
    float*  s_cls = smem;                  // QT*NC
    float4* s_qb  = (float4*)(smem + QT * NC);

    const int i0 = blockIdx.y * QT;
    const int j  = blockIdx.x * BLK + threadIdx.x;

    for (int t = threadIdx.x; t < QT * NC; t += BLK) {
        const int qi = i0 + t / NC;
        float v = 0.0f;
        if (qi < NQB) {
            const float x  = logits[qi * NC + (t % NC)];
            const float p  = 1.0f / (1.0f + __expf(-x));
            const float om = 1.0f - p;
            v = 0.25f * om * om * (-__logf(p + 1e-8f))
              - 0.75f * p * p * (-__logf(om + 1e-8f));
        }
        s_cls[t] = v;
    }
    if (threadIdx.x < QT) {
        const int qi = i0 + threadIdx.x;
        s_qb[threadIdx.x] = (qi < NQB) ? ((const float4*)pboxes)[qi]
                                       : make_float4(0.f, 0.f, 0.f, 0.f);
    }
    __syncthreads();
    if (j >= NT) return;

    const float4 tb = ((const float4*)tboxes)[j];
    const int   lab = labels[j];
    const float tx0 = tb.x - 0.5f * tb.z, tx1 = tb.x + 0.5f * tb.z;
    const float ty0 = tb.y - 0.5f * tb.w, ty1 = tb.y + 0.5f * tb.w;
    const float ta  = tb.z * tb.w;

#pragma unroll
    for (int q = 0; q < QT; ++q) {
        const float4 qb = s_qb[q];
        const float ccls = s_cls[q * NC + lab];
        const float l1 = fabsf(qb.x - tb.x) + fabsf(qb.y - tb.y)
                       + fabsf(qb.z - tb.z) + fabsf(qb.w - tb.w);
        const float qx0 = qb.x - 0.5f * qb.z, qx1 = qb.x + 0.5f * qb.z;
        const float qy0 = qb.y - 0.5f * qb.w, qy1 = qb.y + 0.5f * qb.w;
        const float qa  = qb.z * qb.w;
        const float ltx = fmaxf(qx0, tx0), lty = fmaxf(qy0, ty0);
        const float rbx = fminf(qx1, tx1), rby = fminf(qy1, ty1);
        const float iw = fmaxf(rbx - ltx, 0.f), ih = fmaxf(rby - lty, 0.f);
        const float inter = iw * ih;
        const float uni   = qa + ta - inter;
        const float iou   = inter * __builtin_amdgcn_rcpf(fmaxf(uni, 1e-6f));
        const float ex0 = fminf(qx0, tx0), ey0 = fminf(qy0, ty0);
        const float ex1 = fmaxf(qx1, tx1), ey1 = fmaxf(qy1, ty1);
        const float ew = fmaxf(ex1 - ex0, 0.f), eh = fmaxf(ey1 - ey0, 0.f);
        const float encl = ew * eh;
        const float giou = iou - (encl - uni) * __builtin_amdgcn_rcpf(fmaxf(encl, 1e-6f));
        float cc = 5.0f * l1 + 2.0f * ccls - 2.0f * giou;
        cc = (cc == cc) ? cc : 1.0f;
        const int qi = i0 + q;
        if (qi < NQB) out[(size_t)qi * NT + j] = cc;
    }
}

extern "C" void kernel_launch(void* const* d_in, const int* in_sizes, int n_in,
                              void* d_out, int out_size, void* d_ws, size_t ws_size,
                              hipStream_t stream) {
    const float* logits = (const float*)d_in[0];
    const float* pboxes = (const float*)d_in[1];
    const int*   labels = (const int*)d_in[2];
    const float* tboxes = (const float*)d_in[3];
    float*       out    = (float*)d_out;

    const int nqb = in_sizes[1] / 4;
    const int nt  = in_sizes[2];
    const int nc  = in_sizes[0] / nqb;

    if (nqb == NQB_C && nt == NT_C && nc == NCC) {
        const int nblk = TOTAL / WPB;                // 1875, exact
        hipLaunchKernelGGL(cost_fast, dim3(nblk), dim3(BLK), 0, stream,
                           logits, pboxes, labels, tboxes, out);
    } else {
        dim3 grid((nt + BLK - 1) / BLK, (nqb + QT - 1) / QT);
        size_t sm = QT * nc * sizeof(float) + QT * sizeof(float4);
        hipLaunchKernelGGL(cost_generic, grid, dim3(BLK), sm, stream,
                           logits, pboxes, labels, tboxes, out, nqb, nt, nc);
    }
}

// Round 18
// 50.350 us; speedup vs baseline: 1.0183x; 1.0183x over previous
//
#include <hip/hip_runtime.h>
#include <cmath>

// Fixed problem shape (reference setup_inputs): bs=16, nq=900, nc=80, nt=3200
#define NCC   80                 // classes
#define QT    8                  // queries per row-group
#define BLK   256                // threads per block
#define VT    4                  // targets per thread-tile (float4 store)
#define NT_C  3200               // targets
#define NQB_C 14400              // bs*nq rows
#define CPR   (NT_C / VT)        // 800 float4-columns per row-group
#define NRG   (NQB_C / QT)       // 1800 row-groups
#define TOTAL (NRG * CPR)        // 1,440,000 work items
#define WPB   (2 * BLK)          // 512 work items per block (2 tiles)
#define CSTR  20                 // class-table row stride in floats (16B-aligned)

typedef float f32x4 __attribute__((ext_vector_type(4)));

__device__ __forceinline__ float cls_cost(float x) {
    // 2*(pos-neg) + 2  : COST_CLASS folded + giou-rewrite constant
    const float p   = 1.0f / (1.0f + __expf(-x));
    const float om  = 1.0f - p;
    const float pos = 0.25f * om * om * (-__logf(p  + 1e-8f));
    const float neg = 0.75f * p  * p  * (-__logf(om + 1e-8f));
    return 2.0f * (pos - neg) + 2.0f;
}

// Compute + store one tile's 8 queries x 4 targets (R14 math, NT stores).
__device__ __forceinline__ void tile_compute(
    int g8, unsigned obase,
    const int labk[VT], const float4 tb[VT], const float ta[VT],
    const float* __restrict__ s_cls, const float4* __restrict__ s_qb,
    float* __restrict__ out)
{
#pragma unroll
    for (int h = 0; h < 2; ++h) {
        const int qbase = g8 + h * 4;
        float4 c2v[VT];
#pragma unroll
        for (int k = 0; k < VT; ++k)
            c2v[k] = *(const float4*)&s_cls[labk[k] * CSTR + qbase];

        const unsigned offh = obase + (unsigned)h * 4u * NT_C;
#pragma unroll
        for (int q4 = 0; q4 < 4; ++q4) {
            const float4 qb = s_qb[qbase + q4];
            const float  qa = qb.z * qb.w;
            float res[VT];
#pragma unroll
            for (int k = 0; k < VT; ++k) {
                const float c2 = c2v[k][q4];
                const float d1 = qb.x - tb[k].x;
                const float d2 = qb.y - tb[k].y;
                const float d3 = qb.z - tb[k].z;
                const float d4 = qb.w - tb[k].w;
                const float sx = qb.z + tb[k].z;
                const float sy = qb.w + tb[k].w;
                const float dxr = fmaf(0.5f, sx, -fabsf(d1));
                const float dyr = fmaf(0.5f, sy, -fabsf(d2));
                const float dx  = fminf(fminf(dxr, qb.z), tb[k].z);   // v_min3
                const float dy  = fminf(fminf(dyr, qb.w), tb[k].w);
                const float iw  = fmaxf(dx, 0.0f);
                const float ih  = fmaxf(dy, 0.0f);
                const float inter = iw * ih;
                const float uni   = (qa + ta[k]) - inter;
                const float ew = sx - dx;
                const float eh = sy - dy;
                const float encl = ew * eh;
                const float r1 = __builtin_amdgcn_rcpf(fmaxf(uni,  1e-6f));
                const float r2 = __builtin_amdgcn_rcpf(fmaxf(encl, 1e-6f));
                const float l1 = (fabsf(d1) + fabsf(d2)) + (fabsf(d3) + fabsf(d4));
                float cc = fmaf(5.0f, l1, c2);
                cc = fmaf(-2.0f * inter, r1, cc);
                cc = fmaf(-2.0f * uni,  r2, cc);
                res[k] = cc;
            }
            f32x4 v = { res[0], res[1], res[2], res[3] };
            __builtin_nontemporal_store(
                v, (f32x4*)(out + offh + (unsigned)q4 * NT_C));
        }
    }
}

// ---------------- fast kernel ----------------------------------------------
// Best-known configuration (R16, 50.5 us): R14 math + TWO tiles per thread
// (512 work items per block, grid 2813): tile-2's loads/compute issue while
// tile-1's NT stores drain (same wave, no dependency) -> wave-exit store-drain
// amortized over 2x work; staging redundancy halved vs one-tile.
__global__ __launch_bounds__(BLK) void cost_fast(
    const float* __restrict__ logits,   // [NQB_C, NCC]
    const float* __restrict__ pboxes,   // [NQB_C, 4] cxcywh
    const int*   __restrict__ labels,   // [NT_C]
    const float* __restrict__ tboxes,   // [NT_C, 4] cxcywh
    float*       __restrict__ out)      // [NQB_C, NT_C]
{
    __shared__ float4 s_clsv[NCC * (CSTR / 4)];     // [80][20] floats
    __shared__ float4 s_qb[2 * QT];                 // cxcywh
    float* s_cls = (float*)s_clsv;

    const int  w0    = blockIdx.x * WPB;
    const int  rg0   = w0 / CPR;
    const int  row0  = rg0 * QT;
    const int  wlast = min(w0 + WPB - 1, TOTAL - 1);
    const bool two   = ((wlast / CPR) != rg0);      // block spans 2 row-groups?

    // ---- tile 1 indices + pre-barrier loads (always a full tile) ----
    const int w1  = w0 + threadIdx.x;
    const int rg1 = w1 / CPR;
    const int c1  = w1 - rg1 * CPR;
    const int j1  = c1 * VT;
    const int g81 = (rg1 - rg0) * QT;

    const int4 lab4a = ((const int4*)labels)[c1];
    const int labk1[VT] = { lab4a.x, lab4a.y, lab4a.z, lab4a.w };
    float4 tb1[VT];
    float ta1[VT];
#pragma unroll
    for (int k = 0; k < VT; ++k) {
        tb1[k] = ((const float4*)tboxes)[j1 + k];
        ta1[k] = tb1[k].z * tb1[k].w;
    }

    // ---- staging: LINEAR coalesced reads, LDS-scatter writes ----
    {
        const int nst = (two ? 2 * QT : QT) * NCC;   // 640 or 1280
        const float* src = logits + row0 * NCC;
        for (int t = threadIdx.x; t < nst; t += BLK) {
            const int ro  = t / NCC;                 // row offset 0..15
            const int lab = t - ro * NCC;
            s_cls[lab * CSTR + ro] = cls_cost(src[t]);
        }
    }
    const int ng = two ? 2 * QT : QT;
    if (threadIdx.x < ng) {
        s_qb[threadIdx.x] = ((const float4*)pboxes)[row0 + threadIdx.x];
    }
    __syncthreads();

    // ---- tile 1: compute + store burst ----
    tile_compute(g81, (unsigned)(rg1 * QT) * NT_C + (unsigned)j1,
                 labk1, tb1, ta1, s_cls, s_qb, out);

    // ---- tile 2: loads + compute overlap tile-1 store drain ----
    const int w2 = w0 + BLK + threadIdx.x;
    if (w2 < TOTAL) {
        const int rg2 = w2 / CPR;
        const int c2  = w2 - rg2 * CPR;
        const int j2  = c2 * VT;
        const int g82 = (rg2 - rg0) * QT;

        const int4 lab4b = ((const int4*)labels)[c2];
        const int labk2[VT] = { lab4b.x, lab4b.y, lab4b.z, lab4b.w };
        float4 tb2[VT];
        float ta2[VT];
#pragma unroll
        for (int k = 0; k < VT; ++k) {
            tb2[k] = ((const float4*)tboxes)[j2 + k];
            ta2[k] = tb2[k].z * tb2[k].w;
        }
        tile_compute(g82, (unsigned)(rg2 * QT) * NT_C + (unsigned)j2,
                     labk2, tb2, ta2, s_cls, s_qb, out);
    }
}

// ---------------- generic fallback ------------------------------------------
__global__ __launch_bounds__(BLK) void cost_generic(
    const float* __restrict__ logits, const float* __restrict__ pboxes,
    const int* __restrict__ labels, const float* __restrict__ tboxes,
    float* __restrict__ out, int NQB, int NT, int NC)
{
    extern __shared__ float smem[];
    float*  s_cls = smem;                  // QT*NC
    float4* s_qb  = (float4*)(smem + QT * NC);

    const int i0 = blockIdx.y * QT;
    const int j  = blockIdx.x * BLK + threadIdx.x;

    for (int t = threadIdx.x; t < QT * NC; t += BLK) {
        const int qi = i0 + t / NC;
        float v = 0.0f;
        if (qi < NQB) {
            const float x  = logits[qi * NC + (t % NC)];
            const float p  = 1.0f / (1.0f + __expf(-x));
            const float om = 1.0f - p;
            v = 0.25f * om * om * (-__logf(p + 1e-8f))
              - 0.75f * p * p * (-__logf(om + 1e-8f));
        }
        s_cls[t] = v;
    }
    if (threadIdx.x < QT) {
        const int qi = i0 + threadIdx.x;
        s_qb[threadIdx.x] = (qi < NQB) ? ((const float4*)pboxes)[qi]
                                       : make_float4(0.f, 0.f, 0.f, 0.f);
    }
    __syncthreads();
    if (j >= NT) return;

    const float4 tb = ((const float4*)tboxes)[j];
    const int   lab = labels[j];
    const float tx0 = tb.x - 0.5f * tb.z, tx1 = tb.x + 0.5f * tb.z;
    const float ty0 = tb.y - 0.5f * tb.w, ty1 = tb.y + 0.5f * tb.w;
    const float ta  = tb.z * tb.w;

#pragma unroll
    for (int q = 0; q < QT; ++q) {
        const float4 qb = s_qb[q];
        const float ccls = s_cls[q * NC + lab];
        const float l1 = fabsf(qb.x - tb.x) + fabsf(qb.y - tb.y)
                       + fabsf(qb.z - tb.z) + fabsf(qb.w - tb.w);
        const float qx0 = qb.x - 0.5f * qb.z, qx1 = qb.x + 0.5f * qb.z;
        const float qy0 = qb.y - 0.5f * qb.w, qy1 = qb.y + 0.5f * qb.w;
        const float qa  = qb.z * qb.w;
        const float ltx = fmaxf(qx0, tx0), lty = fmaxf(qy0, ty0);
        const float rbx = fminf(qx1, tx1), rby = fminf(qy1, ty1);
        const float iw = fmaxf(rbx - ltx, 0.f), ih = fmaxf(rby - lty, 0.f);
        const float inter = iw * ih;
        const float uni   = qa + ta - inter;
        const float iou   = inter * __builtin_amdgcn_rcpf(fmaxf(uni, 1e-6f));
        const float ex0 = fminf(qx0, tx0), ey0 = fminf(qy0, ty0);
        const float ex1 = fmaxf(qx1, tx1), ey1 = fmaxf(qy1, ty1);
        const float ew = fmaxf(ex1 - ex0, 0.f), eh = fmaxf(ey1 - ey0, 0.f);
        const float encl = ew * eh;
        const float giou = iou - (encl - uni) * __builtin_amdgcn_rcpf(fmaxf(encl, 1e-6f));
        float cc = 5.0f * l1 + 2.0f * ccls - 2.0f * giou;
        cc = (cc == cc) ? cc : 1.0f;
        const int qi = i0 + q;
        if (qi < NQB) out[(size_t)qi * NT + j] = cc;
    }
}

extern "C" void kernel_launch(void* const* d_in, const int* in_sizes, int n_in,
                              void* d_out, int out_size, void* d_ws, size_t ws_size,
                              hipStream_t stream) {
    const float* logits = (const float*)d_in[0];
    const float* pboxes = (const float*)d_in[1];
    const int*   labels = (const int*)d_in[2];
    const float* tboxes = (const float*)d_in[3];
    float*       out    = (float*)d_out;

    const int nqb = in_sizes[1] / 4;
    const int nt  = in_sizes[2];
    const int nc  = in_sizes[0] / nqb;

    if (nqb == NQB_C && nt == NT_C && nc == NCC) {
        const int nblk = (TOTAL + WPB - 1) / WPB;    // 2813
        hipLaunchKernelGGL(cost_fast, dim3(nblk), dim3(BLK), 0, stream,
                           logits, pboxes, labels, tboxes, out);
    } else {
        dim3 grid((nt + BLK - 1) / BLK, (nqb + QT - 1) / QT);
        size_t sm = QT * nc * sizeof(float) + QT * sizeof(float4);
        hipLaunchKernelGGL(cost_generic, grid, dim3(BLK), sm, stream,
                           logits, pboxes, labels, tboxes, out, nqb, nt, nc);
    }
}